// Round 1
// baseline (356.493 us; speedup 1.0000x reference)
//
#include <hip/hip_runtime.h>
#include <math.h>

// Problem constants
#define HID   4096
#define NH    32
#define D     128
#define I_    4096          // NH*D
#define QKV_ROWS 12288      // 3*I
#define TOTAL_ROWS 16448    // 12288 + 4096 + 32 + 32

// ws layout (floats)
#define WS_QKV   0          // silu(conv(qkv))   [12288]
#define WS_Z     12288      // silu(z)           [4096]
#define WS_AB    16384      // exp(g)[32] then beta[32]
#define WS_VEC   16448      // core_normed * silu(z), 4096 floats

typedef float f4 __attribute__((ext_vector_type(4)));

__device__ __forceinline__ float wave_reduce(float x) {
    for (int off = 32; off > 0; off >>= 1) x += __shfl_down(x, off, 64);
    return x;
}

// ---------------------------------------------------------------------------
// K1: all input matvecs + ALL per-row epilogues fused into lane 0.
// One 64-lane wave per row; 4 rows per 256-thread block. Weights streamed
// once -> nontemporal. Epilogue latency hides among ~16K resident waves,
// removing it from head_fused's 32-block critical path.
//   qkv rows: conv(4-tap)+silu -> ws; new_conv_state -> d_out
//   z rows:   silu(z) -> ws
//   a rows:   exp(g) = exp(-exp(A_log)*softplus(a+dt_bias)) -> ws
//   b rows:   sigmoid(b) -> ws
// ---------------------------------------------------------------------------
__global__ __launch_bounds__(256) void matvec_all(
    const float* __restrict__ h,
    const float* __restrict__ Wqkv, const float* __restrict__ Wz,
    const float* __restrict__ Wa,   const float* __restrict__ Wb,
    const float* __restrict__ conv_state,  // (12288,3)
    const float* __restrict__ conv_w,      // (12288,4)
    const float* __restrict__ conv_b,      // (12288,)
    const float* __restrict__ A_log, const float* __restrict__ dt_bias,
    float* __restrict__ ws,
    float* __restrict__ ncs_out)           // (12288,3)
{
    const int wave = threadIdx.x >> 6;
    const int lane = threadIdx.x & 63;
    const int row  = blockIdx.x * 4 + wave;

    const float* W; int r;
    if (row < QKV_ROWS)          { W = Wqkv; r = row;         }
    else if (row < 16384)        { W = Wz;   r = row - 12288; }
    else if (row < 16416)        { W = Wa;   r = row - 16384; }
    else                         { W = Wb;   r = row - 16416; }

    const f4* wrow = (const f4*)(W + (size_t)r * HID);
    const f4* hv   = (const f4*)h;

    float acc = 0.f;
    #pragma unroll
    for (int i = 0; i < 16; ++i) {
        const f4 wv = __builtin_nontemporal_load(wrow + lane + i * 64);
        const f4 hh = hv[lane + i * 64];
        acc = fmaf(wv.x, hh.x, acc);
        acc = fmaf(wv.y, hh.y, acc);
        acc = fmaf(wv.z, hh.z, acc);
        acc = fmaf(wv.w, hh.w, acc);
    }
    acc = wave_reduce(acc);

    if (lane == 0) {
        if (row < QKV_ROWS) {
            const float* cs = conv_state + (size_t)row * 3;
            const f4 cw = *(const f4*)(conv_w + (size_t)row * 4);
            const float cs0 = cs[0], cs1 = cs[1], cs2 = cs[2];
            const float val = fmaf(cs0, cw.x, fmaf(cs1, cw.y,
                              fmaf(cs2, cw.z, fmaf(acc, cw.w, conv_b[row]))));
            ws[WS_QKV + row] = val / (1.f + expf(-val));   // silu
            ncs_out[(size_t)row * 3 + 0] = cs1;
            ncs_out[(size_t)row * 3 + 1] = cs2;
            ncs_out[(size_t)row * 3 + 2] = acc;
        } else if (row < 16384) {
            ws[WS_Z + (row - 12288)] = acc / (1.f + expf(-acc));  // silu(z)
        } else if (row < 16416) {
            const int rr = row - 16384;
            const float x  = acc + dt_bias[rr];
            const float sp = fmaxf(x, 0.f) + log1pf(expf(-fabsf(x)));  // softplus
            ws[WS_AB + rr] = expf(-expf(A_log[rr]) * sp);              // exp(g)
        } else {
            ws[WS_AB + 32 + (row - 16416)] = 1.f / (1.f + expf(-acc)); // beta
        }
    }
}

// ---------------------------------------------------------------------------
// K2: fused per-head pipeline. 32 blocks x 1024 threads (16 waves).
// Conv/silu/g/beta pre-done in K1; raw state prefetched at kernel entry so
// the 64 KB/block read overlaps the norm phases.
// ---------------------------------------------------------------------------
__global__ __launch_bounds__(1024) void head_fused(
    const float* __restrict__ ws_in,       // silu'd qkv, silu(z), eg/beta
    const float* __restrict__ rnn_state,   // (32,128,128)
    const float* __restrict__ norm_w,
    float* __restrict__ state_out,         // d_out + 4096
    float* __restrict__ vec_out)           // ws + WS_VEC
{
    const int hd   = blockIdx.x;
    const int tid  = threadIdx.x;
    const int e    = tid & 127;
    const int dgrp = tid >> 7;            // 0..7
    const int d0   = dgrp * 16;

    __shared__ float sy[3][D];            // silu(conv) for q,k,v
    __shared__ float skn[D], sqn[D];      // normalized k, q
    __shared__ float pkv[8][D], pcq[8][D];
    __shared__ float pkq[8];
    __shared__ float snrm[2];             // sumsq q, k
    __shared__ float sdelta[D], score[D];
    __shared__ float red[2];

    // ---- Prefetch raw state (independent of every phase below) ----
    const float* Sp = rnn_state + (size_t)hd * D * D + (size_t)d0 * D + e;
    float sreg[16];
    #pragma unroll
    for (int j = 0; j < 16; ++j) sreg[j] = Sp[j * D];

    // ---- Phase A: pull silu'd q,k,v from ws ----
    if (tid < 384) {
        const int j  = tid >> 7;          // 0=q 1=k 2=v
        const int e2 = tid & 127;
        sy[j][e2] = ws_in[WS_QKV + j * I_ + hd * D + e2];
    }
    __syncthreads();

    // ---- Phase B: l2 norms of q (wave 0) and k (wave 1) ----
    if (tid < 128) {
        const int w = tid >> 6, lane = tid & 63;
        const float v0 = sy[w][lane], v1 = sy[w][lane + 64];
        const float ss = wave_reduce(fmaf(v0, v0, v1 * v1));
        if (lane == 0) snrm[w] = ss;
    }
    __syncthreads();
    if (tid < 128) {
        const float invq = (1.f / fmaxf(sqrtf(snrm[0]), 1e-6f)) * 0.08838834764831843f;
        const float invk =  1.f / fmaxf(sqrtf(snrm[1]), 1e-6f);
        sqn[tid] = sy[0][tid] * invq;
        skn[tid] = sy[1][tid] * invk;
    }
    __syncthreads();

    // ---- Phase C: scale state + partial reductions ----
    const float eg   = ws_in[WS_AB + hd];        // exp(g), precomputed
    const float beta = ws_in[WS_AB + 32 + hd];

    float kv = 0.f, cq = 0.f;
    #pragma unroll
    for (int j = 0; j < 16; ++j) {
        sreg[j] *= eg;
        kv = fmaf(sreg[j], skn[d0 + j], kv);
        cq = fmaf(sreg[j], sqn[d0 + j], cq);
    }
    pkv[dgrp][e] = kv;
    pcq[dgrp][e] = cq;
    if (e == 0) {
        float t = 0.f;
        #pragma unroll
        for (int j = 0; j < 16; ++j) t = fmaf(skn[d0 + j], sqn[d0 + j], t);
        pkq[dgrp] = t;
    }
    __syncthreads();

    // ---- Phase D: combine, delta, core, RMS reduce ----
    if (tid < 128) {
        float kvt = 0.f, cqt = 0.f, kq = 0.f;
        #pragma unroll
        for (int g = 0; g < 8; ++g) {
            kvt += pkv[g][tid];
            cqt += pcq[g][tid];
            kq  += pkq[g];
        }
        const float delta = (sy[2][tid] - kvt) * beta;
        sdelta[tid] = delta;
        const float core = fmaf(delta, kq, cqt);
        score[tid] = core;
        const float c2 = wave_reduce(core * core);
        if ((tid & 63) == 0) red[tid >> 6] = c2;
    }
    __syncthreads();

    // ---- Phase E: state store from registers + output vector ----
    float* So = state_out + (size_t)hd * D * D + (size_t)d0 * D + e;
    const float de = sdelta[e];
    #pragma unroll
    for (int j = 0; j < 16; ++j)
        So[j * D] = fmaf(skn[d0 + j], de, sreg[j]);

    if (tid < 128) {
        const float var = (red[0] + red[1]) * (1.f / 128.f);
        const float cn  = norm_w[tid] * score[tid] * rsqrtf(var + 1e-6f);
        vec_out[hd * D + tid] = cn * ws_in[WS_Z + hd * D + tid];  // silu(z) pre-applied
    }
}

// ---------------------------------------------------------------------------
// K3: out = W_out @ vec.  4096 rows, one wave per row. Nontemporal weights.
// ---------------------------------------------------------------------------
__global__ __launch_bounds__(256) void matvec_out(
    const float* __restrict__ Wout, const float* __restrict__ vec,
    float* __restrict__ out)
{
    const int wave = threadIdx.x >> 6;
    const int lane = threadIdx.x & 63;
    const int row  = blockIdx.x * 4 + wave;

    const f4* wrow = (const f4*)(Wout + (size_t)row * I_);
    const f4* xv   = (const f4*)vec;

    float acc = 0.f;
    #pragma unroll
    for (int i = 0; i < 16; ++i) {
        const f4 wv = __builtin_nontemporal_load(wrow + lane + i * 64);
        const f4 xx = xv[lane + i * 64];
        acc = fmaf(wv.x, xx.x, acc);
        acc = fmaf(wv.y, xx.y, acc);
        acc = fmaf(wv.z, xx.z, acc);
        acc = fmaf(wv.w, xx.w, acc);
    }
    acc = wave_reduce(acc);
    if (lane == 0) out[row] = acc;
}

// ---------------------------------------------------------------------------
extern "C" void kernel_launch(void* const* d_in, const int* in_sizes, int n_in,
                              void* d_out, int out_size, void* d_ws, size_t ws_size,
                              hipStream_t stream) {
    const float* hs         = (const float*)d_in[0];   // (4096,)
    const float* rnn_state  = (const float*)d_in[1];   // (32,128,128)
    const float* conv_state = (const float*)d_in[2];   // (12288,3)
    const float* W_qkv      = (const float*)d_in[3];   // (12288,4096)
    const float* W_z        = (const float*)d_in[4];   // (4096,4096)
    const float* W_a        = (const float*)d_in[5];   // (32,4096)
    const float* W_b        = (const float*)d_in[6];   // (32,4096)
    const float* conv_w     = (const float*)d_in[7];   // (12288,4)
    const float* conv_b     = (const float*)d_in[8];   // (12288,)
    const float* A_log      = (const float*)d_in[9];   // (32,)
    const float* dt_bias    = (const float*)d_in[10];  // (32,)
    const float* norm_w     = (const float*)d_in[11];  // (128,)
    const float* W_out      = (const float*)d_in[12];  // (4096,4096)

    float* out       = (float*)d_out;                     // [0, 4096)
    float* state_out = (float*)d_out + 4096;              // [4096, 528384)
    float* ncs_out   = (float*)d_out + 4096 + NH * D * D; // [528384, 565248)
    float* ws        = (float*)d_ws;

    matvec_all<<<TOTAL_ROWS / 4, 256, 0, stream>>>(hs, W_qkv, W_z, W_a, W_b,
                                                   conv_state, conv_w, conv_b,
                                                   A_log, dt_bias, ws, ncs_out);
    head_fused<<<NH, 1024, 0, stream>>>(ws, rnn_state, norm_w,
                                        state_out, ws + WS_VEC);
    matvec_out<<<I_ / 4, 256, 0, stream>>>(W_out, ws + WS_VEC, out);
}

// Round 3
// 355.987 us; speedup vs baseline: 1.0014x; 1.0014x over previous
//
#include <hip/hip_runtime.h>
#include <math.h>

// Problem constants
#define HID   4096
#define NH    32
#define D     128
#define I_    4096          // NH*D
#define QKV_ROWS 12288      // 3*I
#define TOTAL_ROWS 16448    // 12288 + 4096 + 32 + 32

// ws layout (floats)
#define WS_QKV   0          // silu(conv(qkv))   [12288]
#define WS_Z     12288      // silu(z)           [4096]
#define WS_AB    16384      // exp(g)[32] then beta[32]
#define WS_VEC   16448      // core_normed * silu(z), 4096 floats

typedef float f4 __attribute__((ext_vector_type(4)));

__device__ __forceinline__ float wave_reduce(float x) {
    for (int off = 32; off > 0; off >>= 1) x += __shfl_down(x, off, 64);
    return x;
}

// Per-row epilogue for K1 (runs on lane 0 only).
__device__ __forceinline__ void k1_epilogue(
    int row, float acc, float* __restrict__ ws,
    const float* __restrict__ conv_state, const float* __restrict__ conv_w,
    const float* __restrict__ conv_b,
    const float* __restrict__ A_log, const float* __restrict__ dt_bias,
    float* __restrict__ ncs_out)
{
    if (row < QKV_ROWS) {
        const float* cs = conv_state + (size_t)row * 3;
        const f4 cw = *(const f4*)(conv_w + (size_t)row * 4);
        const float cs0 = cs[0], cs1 = cs[1], cs2 = cs[2];
        const float val = fmaf(cs0, cw.x, fmaf(cs1, cw.y,
                          fmaf(cs2, cw.z, fmaf(acc, cw.w, conv_b[row]))));
        ws[WS_QKV + row] = val / (1.f + expf(-val));   // silu
        ncs_out[(size_t)row * 3 + 0] = cs1;
        ncs_out[(size_t)row * 3 + 1] = cs2;
        ncs_out[(size_t)row * 3 + 2] = acc;
    } else if (row < 16384) {
        ws[WS_Z + (row - 12288)] = acc / (1.f + expf(-acc));  // silu(z)
    } else if (row < 16416) {
        const int rr = row - 16384;
        const float x  = acc + dt_bias[rr];
        const float sp = fmaxf(x, 0.f) + log1pf(expf(-fabsf(x)));  // softplus
        ws[WS_AB + rr] = expf(-expf(A_log[rr]) * sp);              // exp(g)
    } else {
        ws[WS_AB + 32 + (row - 16416)] = 1.f / (1.f + expf(-acc)); // beta
    }
}

// ---------------------------------------------------------------------------
// K1: all input matvecs, TWO rows per wave (8 rows per 256-thread block).
// Doubles outstanding nontemporal weight loads per wave (MLP: ~16 KB in
// flight/CU vs the ~9.2 KB Little's-law requirement at 6.3 TB/s), halves
// h reloads + address setup, two independent FMA chains.
// ---------------------------------------------------------------------------
__global__ __launch_bounds__(256) void matvec_all(
    const float* __restrict__ h,
    const float* __restrict__ Wqkv, const float* __restrict__ Wz,
    const float* __restrict__ Wa,   const float* __restrict__ Wb,
    const float* __restrict__ conv_state,  // (12288,3)
    const float* __restrict__ conv_w,      // (12288,4)
    const float* __restrict__ conv_b,      // (12288,)
    const float* __restrict__ A_log, const float* __restrict__ dt_bias,
    float* __restrict__ ws,
    float* __restrict__ ncs_out)           // (12288,3)
{
    const int wave = threadIdx.x >> 6;
    const int lane = threadIdx.x & 63;
    const int row0 = blockIdx.x * 8 + wave * 2;   // this wave: row0, row0+1

    // Region boundaries (12288, 16384, 16416) are even -> a row pair never
    // straddles two weight matrices.
    const float* W; int r;
    if (row0 < QKV_ROWS)         { W = Wqkv; r = row0;         }
    else if (row0 < 16384)       { W = Wz;   r = row0 - 12288; }
    else if (row0 < 16416)       { W = Wa;   r = row0 - 16384; }
    else                         { W = Wb;   r = row0 - 16416; }

    const f4* w0 = (const f4*)(W + (size_t)r       * HID);
    const f4* w1 = (const f4*)(W + (size_t)(r + 1) * HID);
    const f4* hv = (const f4*)h;

    float a0 = 0.f, a1 = 0.f;
    #pragma unroll
    for (int i = 0; i < 16; ++i) {
        const f4 hh  = hv[lane + i * 64];
        const f4 wv0 = __builtin_nontemporal_load(w0 + lane + i * 64);
        const f4 wv1 = __builtin_nontemporal_load(w1 + lane + i * 64);
        a0 = fmaf(wv0.x, hh.x, a0);
        a0 = fmaf(wv0.y, hh.y, a0);
        a0 = fmaf(wv0.z, hh.z, a0);
        a0 = fmaf(wv0.w, hh.w, a0);
        a1 = fmaf(wv1.x, hh.x, a1);
        a1 = fmaf(wv1.y, hh.y, a1);
        a1 = fmaf(wv1.z, hh.z, a1);
        a1 = fmaf(wv1.w, hh.w, a1);
    }
    a0 = wave_reduce(a0);
    a1 = wave_reduce(a1);

    if (lane == 0) {
        k1_epilogue(row0,     a0, ws, conv_state, conv_w, conv_b, A_log, dt_bias, ncs_out);
        k1_epilogue(row0 + 1, a1, ws, conv_state, conv_w, conv_b, A_log, dt_bias, ncs_out);
    }
}

// ---------------------------------------------------------------------------
// K2: fused per-head pipeline. 32 blocks x 1024 threads (16 waves).
// Conv/silu/g/beta pre-done in K1; raw state prefetched at kernel entry so
// the 64 KB/block read overlaps the norm phases.
// ---------------------------------------------------------------------------
__global__ __launch_bounds__(1024) void head_fused(
    const float* __restrict__ ws_in,       // silu'd qkv, silu(z), eg/beta
    const float* __restrict__ rnn_state,   // (32,128,128)
    const float* __restrict__ norm_w,
    float* __restrict__ state_out,         // d_out + 4096
    float* __restrict__ vec_out)           // ws + WS_VEC
{
    const int hd   = blockIdx.x;
    const int tid  = threadIdx.x;
    const int e    = tid & 127;
    const int dgrp = tid >> 7;            // 0..7
    const int d0   = dgrp * 16;

    __shared__ float sy[3][D];            // silu(conv) for q,k,v
    __shared__ float skn[D], sqn[D];      // normalized k, q
    __shared__ float pkv[8][D], pcq[8][D];
    __shared__ float pkq[8];
    __shared__ float snrm[2];             // sumsq q, k
    __shared__ float sdelta[D], score[D];
    __shared__ float red[2];

    // ---- Prefetch raw state (independent of every phase below) ----
    const float* Sp = rnn_state + (size_t)hd * D * D + (size_t)d0 * D + e;
    float sreg[16];
    #pragma unroll
    for (int j = 0; j < 16; ++j) sreg[j] = Sp[j * D];

    // ---- Phase A: pull silu'd q,k,v from ws ----
    if (tid < 384) {
        const int j  = tid >> 7;          // 0=q 1=k 2=v
        const int e2 = tid & 127;
        sy[j][e2] = ws_in[WS_QKV + j * I_ + hd * D + e2];
    }
    __syncthreads();

    // ---- Phase B: l2 norms of q (wave 0) and k (wave 1) ----
    if (tid < 128) {
        const int w = tid >> 6, lane = tid & 63;
        const float v0 = sy[w][lane], v1 = sy[w][lane + 64];
        const float ss = wave_reduce(fmaf(v0, v0, v1 * v1));
        if (lane == 0) snrm[w] = ss;
    }
    __syncthreads();
    if (tid < 128) {
        const float invq = (1.f / fmaxf(sqrtf(snrm[0]), 1e-6f)) * 0.08838834764831843f;
        const float invk =  1.f / fmaxf(sqrtf(snrm[1]), 1e-6f);
        sqn[tid] = sy[0][tid] * invq;
        skn[tid] = sy[1][tid] * invk;
    }
    __syncthreads();

    // ---- Phase C: scale state + partial reductions ----
    const float eg   = ws_in[WS_AB + hd];        // exp(g), precomputed
    const float beta = ws_in[WS_AB + 32 + hd];

    float kv = 0.f, cq = 0.f;
    #pragma unroll
    for (int j = 0; j < 16; ++j) {
        sreg[j] *= eg;
        kv = fmaf(sreg[j], skn[d0 + j], kv);
        cq = fmaf(sreg[j], sqn[d0 + j], cq);
    }
    pkv[dgrp][e] = kv;
    pcq[dgrp][e] = cq;
    if (e == 0) {
        float t = 0.f;
        #pragma unroll
        for (int j = 0; j < 16; ++j) t = fmaf(skn[d0 + j], sqn[d0 + j], t);
        pkq[dgrp] = t;
    }
    __syncthreads();

    // ---- Phase D: combine, delta, core, RMS reduce ----
    if (tid < 128) {
        float kvt = 0.f, cqt = 0.f, kq = 0.f;
        #pragma unroll
        for (int g = 0; g < 8; ++g) {
            kvt += pkv[g][tid];
            cqt += pcq[g][tid];
            kq  += pkq[g];
        }
        const float delta = (sy[2][tid] - kvt) * beta;
        sdelta[tid] = delta;
        const float core = fmaf(delta, kq, cqt);
        score[tid] = core;
        const float c2 = wave_reduce(core * core);
        if ((tid & 63) == 0) red[tid >> 6] = c2;
    }
    __syncthreads();

    // ---- Phase E: state store from registers + output vector ----
    float* So = state_out + (size_t)hd * D * D + (size_t)d0 * D + e;
    const float de = sdelta[e];
    #pragma unroll
    for (int j = 0; j < 16; ++j)
        So[j * D] = fmaf(skn[d0 + j], de, sreg[j]);

    if (tid < 128) {
        const float var = (red[0] + red[1]) * (1.f / 128.f);
        const float cn  = norm_w[tid] * score[tid] * rsqrtf(var + 1e-6f);
        vec_out[hd * D + tid] = cn * ws_in[WS_Z + hd * D + tid];  // silu(z) pre-applied
    }
}

// ---------------------------------------------------------------------------
// K3: out = W_out @ vec. TWO rows per wave (8 rows / 256-thread block),
// same MLP reasoning as K1.
// ---------------------------------------------------------------------------
__global__ __launch_bounds__(256) void matvec_out(
    const float* __restrict__ Wout, const float* __restrict__ vec,
    float* __restrict__ out)
{
    const int wave = threadIdx.x >> 6;
    const int lane = threadIdx.x & 63;
    const int row0 = blockIdx.x * 8 + wave * 2;

    const f4* w0 = (const f4*)(Wout + (size_t)row0       * I_);
    const f4* w1 = (const f4*)(Wout + (size_t)(row0 + 1) * I_);
    const f4* xv = (const f4*)vec;

    float a0 = 0.f, a1 = 0.f;
    #pragma unroll
    for (int i = 0; i < 16; ++i) {
        const f4 xx  = xv[lane + i * 64];
        const f4 wv0 = __builtin_nontemporal_load(w0 + lane + i * 64);
        const f4 wv1 = __builtin_nontemporal_load(w1 + lane + i * 64);
        a0 = fmaf(wv0.x, xx.x, a0);
        a0 = fmaf(wv0.y, xx.y, a0);
        a0 = fmaf(wv0.z, xx.z, a0);
        a0 = fmaf(wv0.w, xx.w, a0);
        a1 = fmaf(wv1.x, xx.x, a1);
        a1 = fmaf(wv1.y, xx.y, a1);
        a1 = fmaf(wv1.z, xx.z, a1);
        a1 = fmaf(wv1.w, xx.w, a1);
    }
    a0 = wave_reduce(a0);
    a1 = wave_reduce(a1);
    if (lane == 0) {
        out[row0]     = a0;
        out[row0 + 1] = a1;
    }
}

// ---------------------------------------------------------------------------
extern "C" void kernel_launch(void* const* d_in, const int* in_sizes, int n_in,
                              void* d_out, int out_size, void* d_ws, size_t ws_size,
                              hipStream_t stream) {
    const float* hs         = (const float*)d_in[0];   // (4096,)
    const float* rnn_state  = (const float*)d_in[1];   // (32,128,128)
    const float* conv_state = (const float*)d_in[2];   // (12288,3)
    const float* W_qkv      = (const float*)d_in[3];   // (12288,4096)
    const float* W_z        = (const float*)d_in[4];   // (4096,4096)
    const float* W_a        = (const float*)d_in[5];   // (32,4096)
    const float* W_b        = (const float*)d_in[6];   // (32,4096)
    const float* conv_w     = (const float*)d_in[7];   // (12288,4)
    const float* conv_b     = (const float*)d_in[8];   // (12288,)
    const float* A_log      = (const float*)d_in[9];   // (32,)
    const float* dt_bias    = (const float*)d_in[10];  // (32,)
    const float* norm_w     = (const float*)d_in[11];  // (128,)
    const float* W_out      = (const float*)d_in[12];  // (4096,4096)

    float* out       = (float*)d_out;                     // [0, 4096)
    float* state_out = (float*)d_out + 4096;              // [4096, 528384)
    float* ncs_out   = (float*)d_out + 4096 + NH * D * D; // [528384, 565248)
    float* ws        = (float*)d_ws;

    matvec_all<<<TOTAL_ROWS / 8, 256, 0, stream>>>(hs, W_qkv, W_z, W_a, W_b,
                                                   conv_state, conv_w, conv_b,
                                                   A_log, dt_bias, ws, ncs_out);
    head_fused<<<NH, 1024, 0, stream>>>(ws, rnn_state, norm_w,
                                        state_out, ws + WS_VEC);
    matvec_out<<<I_ / 8, 256, 0, stream>>>(W_out, ws + WS_VEC, out);
}